// Round 3
// baseline (560.826 us; speedup 1.0000x reference)
//
#include <hip/hip_runtime.h>

#define B_   32
#define S_   2048
#define D_   512
#define H_   32
#define BS_  (B_*S_)
#define INV_SCALE 0.17677669529663689f   // 1/sqrt(32)

// workspace layout (float offsets) — total 320 KB (known-safe)
#define PT_OFF    0                       // [32][512] transposed projector
#define V_OFF     16384                   // [B][S] scores -> coefficients in place

__device__ __forceinline__ float sigmoidf_(float x) {
    return 1.0f / (1.0f + __expf(-x));
}

// ---------------- transpose projector: PT[j][d] = P[d][j] ----------------
__global__ void kTranspose(const float* __restrict__ P, float* __restrict__ PT) {
    int o = blockIdx.x * 256 + threadIdx.x;      // 16384 total
    int j = o >> 9, d = o & 511;
    PT[o] = P[d * H_ + j];
}

// ---------------- scores: 64 rows/block, 128 threads, LDS-staged GEMM ----
#define KC        64                     // k-chunk (floats)
#define NCHUNKS   (D_ / KC)              // 8
#define XST       68                     // padded LDS row stride (floats), 272 B (16B-aligned)

__global__ __launch_bounds__(128, 3) void kScores(
        const float* __restrict__ inp, const int* __restrict__ mask,
        const float* __restrict__ PT, const float* __restrict__ hd,
        const float* __restrict__ ev, float* __restrict__ v) {
    __shared__ float smem[(64 + 32) * XST];      // 6528 floats = 26112 B
    float* xs = smem;                            // [64][XST] x-chunk
    float* ps = smem + 64 * XST;                 // [32][XST] PT-chunk
    float* w0 = smem;                            // overlay after K-loop: [64][33]
    float* w1 = smem + 64 * 33;                  // overlay: [64][33]

    const int tid = threadIdx.x;
    const int rowBase = blockIdx.x * 64;
    const int cg = tid & 7;      // col j = cg + 8*jj
    const int rg = tid >> 3;     // row = rg + 16*r   (rg 0..15)

    const float4* inp4 = (const float4*)inp;
    const float4* PT4  = (const float4*)PT;

    // staging indices: xs needs 1024 float4 (8/thread), ps 512 float4 (4/thread)
    int xrow[8], xq[8];
    #pragma unroll
    for (int i = 0; i < 8; ++i) {
        int flat = i * 128 + tid;
        xrow[i] = flat >> 4; xq[i] = flat & 15;
    }
    int prow[4], pq[4];
    #pragma unroll
    for (int i = 0; i < 4; ++i) {
        int flat = i * 128 + tid;
        prow[i] = flat >> 4; pq[i] = flat & 15;
    }

    float4 acc[4][4];
    #pragma unroll
    for (int r = 0; r < 4; ++r)
        #pragma unroll
        for (int j = 0; j < 4; ++j)
            acc[r][j] = make_float4(0.f, 0.f, 0.f, 0.f);

    float4 rx[8], rp[4];
    // prefetch chunk 0
    #pragma unroll
    for (int i = 0; i < 8; ++i)
        rx[i] = inp4[(size_t)(rowBase + xrow[i]) * 128 + xq[i]];
    #pragma unroll
    for (int i = 0; i < 4; ++i)
        rp[i] = PT4[(size_t)prow[i] * 128 + pq[i]];

    for (int c = 0; c < NCHUNKS; ++c) {
        __syncthreads();                 // previous compute done, LDS free
        #pragma unroll
        for (int i = 0; i < 8; ++i)
            ((float4*)(xs + xrow[i] * XST))[xq[i]] = rx[i];
        #pragma unroll
        for (int i = 0; i < 4; ++i)
            ((float4*)(ps + prow[i] * XST))[pq[i]] = rp[i];
        __syncthreads();

        if (c + 1 < NCHUNKS) {           // prefetch next chunk (async vs compute)
            int ko = (c + 1) * (KC / 4);
            #pragma unroll
            for (int i = 0; i < 8; ++i)
                rx[i] = inp4[(size_t)(rowBase + xrow[i]) * 128 + ko + xq[i]];
            #pragma unroll
            for (int i = 0; i < 4; ++i)
                rp[i] = PT4[(size_t)prow[i] * 128 + ko + pq[i]];
        }

        #pragma unroll
        for (int kq = 0; kq < KC / 4; ++kq) {
            float4 x4[4], p4[4];
            #pragma unroll
            for (int r = 0; r < 4; ++r)
                x4[r] = ((const float4*)(xs + (rg + 16 * r) * XST))[kq];
            #pragma unroll
            for (int j = 0; j < 4; ++j)
                p4[j] = ((const float4*)(ps + (cg + 8 * j) * XST))[kq];
            #pragma unroll
            for (int r = 0; r < 4; ++r)
                #pragma unroll
                for (int j = 0; j < 4; ++j) {
                    acc[r][j].x = fmaf(x4[r].x, p4[j].x, acc[r][j].x);
                    acc[r][j].y = fmaf(x4[r].y, p4[j].y, acc[r][j].y);
                    acc[r][j].z = fmaf(x4[r].z, p4[j].z, acc[r][j].z);
                    acc[r][j].w = fmaf(x4[r].w, p4[j].w, acc[r][j].w);
                }
        }
    }

    float mr[4];
    #pragma unroll
    for (int r = 0; r < 4; ++r)
        mr[r] = (mask[rowBase + rg + 16 * r] != 0) ? 1.0f : 0.0f;

    __syncthreads();                     // all LDS reads done before overlay
    #pragma unroll
    for (int r = 0; r < 4; ++r) {
        int row = rg + 16 * r;
        #pragma unroll
        for (int j = 0; j < 4; ++j) {
            float s = (acc[r][j].x + acc[r][j].y) + (acc[r][j].z + acc[r][j].w);
            w0[row * 33 + cg + 8 * j] = sigmoidf_(mr[r] * s * INV_SCALE);
        }
    }
    __syncthreads();

    // hidden layer: w1[row][k] = sigmoid(sum_j w0[row][j]*hd[j][k] / scale)
    {
        const int k = tid & 31, half = tid >> 5;   // 4 row slots
        #pragma unroll 4
        for (int t = 0; t < 16; ++t) {
            int row = half + 4 * t;
            float s = 0.f;
            #pragma unroll
            for (int j = 0; j < 32; ++j)
                s = fmaf(w0[row * 33 + j], hd[j * 32 + k], s);
            w1[row * 33 + k] = sigmoidf_(s * INV_SCALE);
        }
    }
    __syncthreads();

    // evaluator: v[row] = sigmoid(sum_k w1[row][k]*ev[k] / scale)
    if (tid < 64) {
        float s = 0.f;
        #pragma unroll
        for (int k = 0; k < 32; ++k)
            s = fmaf(w1[tid * 33 + k], ev[k], s);
        v[rowBase + tid] = sigmoidf_(s * INV_SCALE);
    }
}

// ---- per-b stats + in-place coefficient write (no max-sub: v in (0,1)) ----
__global__ __launch_bounds__(256) void kCoeff(
        float* __restrict__ v, const int* __restrict__ mask) {
    const int b = blockIdx.x, tid = threadIdx.x;
    __shared__ float sr[8];

    float ee[8], mm[8];
    float z = 0.f, dm = 0.f;
    #pragma unroll
    for (int i = 0; i < 8; ++i) {
        int idx = b * S_ + i * 256 + tid;
        ee[i] = __expf(v[idx]);
        mm[i] = (mask[idx] != 0) ? 1.0f : 0.0f;
        z += ee[i];
        dm = fmaf(mm[i], ee[i], dm);
    }
    #pragma unroll
    for (int o = 32; o > 0; o >>= 1) {
        z  += __shfl_down(z, o);
        dm += __shfl_down(dm, o);
    }
    if ((tid & 63) == 0) { sr[tid >> 6] = z; sr[4 + (tid >> 6)] = dm; }
    __syncthreads();
    float Z  = (sr[0] + sr[1]) + (sr[2] + sr[3]);
    float DM = (sr[4] + sr[5]) + (sr[6] + sr[7]);
    float invDen = 1.0f / (DM + 1e-12f * Z);
    #pragma unroll
    for (int i = 0; i < 8; ++i) {
        int idx = b * S_ + i * 256 + tid;
        v[idx] = mm[i] * ee[i] * invDen;
    }
}

// ---- weighted sum, direct to out: block = (b, 64-float d-chunk), 1024 thr ----
__global__ __launch_bounds__(1024) void kOut(
        const float* __restrict__ inp, const float* __restrict__ coeff,
        float* __restrict__ out) {
    const int b = blockIdx.x >> 3, dc = blockIdx.x & 7;
    const int tid = threadIdx.x;
    const int sg = tid >> 4, dl = tid & 15;   // 64 s-groups x 16 float4-lanes
    __shared__ float  cw[S_];
    __shared__ float4 red[1024];

    cw[tid]        = coeff[b * S_ + tid];
    cw[tid + 1024] = coeff[b * S_ + tid + 1024];
    __syncthreads();

    const float4* xp = (const float4*)inp + (size_t)b * S_ * 128 + dc * 16 + dl;
    float4 a0 = make_float4(0,0,0,0), a1 = a0, a2 = a0, a3 = a0;
    #pragma unroll 2
    for (int i = 0; i < 32; i += 4) {
        int s0 = sg + 64 * i;
        float4 x0 = xp[(size_t)(s0      ) * 128];
        float4 x1 = xp[(size_t)(s0 +  64) * 128];
        float4 x2 = xp[(size_t)(s0 + 128) * 128];
        float4 x3 = xp[(size_t)(s0 + 192) * 128];
        float c0 = cw[s0], c1 = cw[s0 + 64], c2 = cw[s0 + 128], c3 = cw[s0 + 192];
        a0.x = fmaf(c0, x0.x, a0.x); a0.y = fmaf(c0, x0.y, a0.y);
        a0.z = fmaf(c0, x0.z, a0.z); a0.w = fmaf(c0, x0.w, a0.w);
        a1.x = fmaf(c1, x1.x, a1.x); a1.y = fmaf(c1, x1.y, a1.y);
        a1.z = fmaf(c1, x1.z, a1.z); a1.w = fmaf(c1, x1.w, a1.w);
        a2.x = fmaf(c2, x2.x, a2.x); a2.y = fmaf(c2, x2.y, a2.y);
        a2.z = fmaf(c2, x2.z, a2.z); a2.w = fmaf(c2, x2.w, a2.w);
        a3.x = fmaf(c3, x3.x, a3.x); a3.y = fmaf(c3, x3.y, a3.y);
        a3.z = fmaf(c3, x3.z, a3.z); a3.w = fmaf(c3, x3.w, a3.w);
    }
    float4 a;
    a.x = (a0.x + a1.x) + (a2.x + a3.x);
    a.y = (a0.y + a1.y) + (a2.y + a3.y);
    a.z = (a0.z + a1.z) + (a2.z + a3.z);
    a.w = (a0.w + a1.w) + (a2.w + a3.w);
    red[tid] = a;
    __syncthreads();

    #pragma unroll
    for (int h = 32; h >= 1; h >>= 1) {
        if (sg < h) {
            float4 p = red[(sg + h) * 16 + dl];
            float4 q = red[tid];
            q.x += p.x; q.y += p.y; q.z += p.z; q.w += p.w;
            red[tid] = q;
        }
        __syncthreads();
    }
    if (tid < 16)
        ((float4*)out)[b * 128 + dc * 16 + tid] = red[tid];
}

extern "C" void kernel_launch(void* const* d_in, const int* in_sizes, int n_in,
                              void* d_out, int out_size, void* d_ws, size_t ws_size,
                              hipStream_t stream) {
    const float* inp  = (const float*)d_in[0];
    const int*   mask = (const int*)d_in[1];
    const float* proj = (const float*)d_in[2];
    const float* hid  = (const float*)d_in[3];   // [1][32][32]
    const float* ev   = (const float*)d_in[4];   // [32]
    float* out = (float*)d_out;
    float* ws  = (float*)d_ws;

    float* PT = ws + PT_OFF;
    float* v  = ws + V_OFF;

    kTranspose<<<64, 256, 0, stream>>>(proj, PT);
    kScores   <<<BS_ / 64, 128, 0, stream>>>(inp, mask, PT, hid, ev, v);
    kCoeff    <<<B_, 256, 0, stream>>>(v, mask);
    kOut      <<<B_ * 8, 1024, 0, stream>>>(inp, v, out);
}

// Round 4
// 237.758 us; speedup vs baseline: 2.3588x; 2.3588x over previous
//
#include <hip/hip_runtime.h>

#define B_   32
#define S_   2048
#define D_   512
#define H_   32
#define BS_  (B_*S_)
#define INV_SCALE 0.17677669529663689f   // 1/sqrt(32)

// workspace layout — total 294912 bytes (< 320 KB proven-safe)
// bytes [0, 32768):       PTbf  ushort[32][512]  (bf16 transposed projector)
// bytes [32768, 294912):  v     float[B][S]      (scores -> coefficients, sign-tagged)

typedef short  s16x8 __attribute__((ext_vector_type(8)));
typedef float  f32x4 __attribute__((ext_vector_type(4)));

__device__ __forceinline__ float sigmoidf_(float x) {
    return 1.0f / (1.0f + __expf(-x));
}

__device__ __forceinline__ unsigned short f2bf(float f) {
    unsigned u = __float_as_uint(f);
    u += 0x7fffu + ((u >> 16) & 1u);     // round-to-nearest-even
    return (unsigned short)(u >> 16);
}

// ---------------- transpose projector to bf16: PTbf[j][d] = bf16(P[d][j]) ----------------
__global__ void kTransposeBf(const float* __restrict__ P, unsigned short* __restrict__ PTbf) {
    int o = blockIdx.x * 256 + threadIdx.x;      // 16384 total
    int j = o >> 9, d = o & 511;
    PTbf[o] = f2bf(P[d * H_ + j]);
}

// ---------------- scores via MFMA: 32 rows/block, 256 threads ----------------
#define XST 520                               // bf16 row stride in LDS (512 + 8 pad)

__global__ __launch_bounds__(256) void kScores(
        const float* __restrict__ inp, const int* __restrict__ mask,
        const unsigned short* __restrict__ PTbf, const float* __restrict__ hd,
        const float* __restrict__ ev, float* __restrict__ v) {
    __shared__ unsigned short xs[32 * XST];   // 33280 B
    float* w0f = (float*)xs;                  // overlay after MFMA phase: [32][33]
    float* w1f = ((float*)xs) + 32 * 33;      // overlay: [32][33]

    const int tid = threadIdx.x;
    const int rowBase = blockIdx.x * 32;

    // ---- stage x tile (32 rows x 512 fp32 = 64 KB) -> LDS bf16, fully coalesced ----
    const float4* g = (const float4*)inp + (size_t)rowBase * 128;
    float4 tmp[16];
    #pragma unroll
    for (int i = 0; i < 16; ++i)
        tmp[i] = g[i * 256 + tid];            // flat index == row*128 + kq (contiguous)
    #pragma unroll
    for (int i = 0; i < 16; ++i) {
        int fi = i * 256 + tid;
        int row = fi >> 7, kq = fi & 127;
        ushort4 u;
        u.x = f2bf(tmp[i].x); u.y = f2bf(tmp[i].y);
        u.z = f2bf(tmp[i].z); u.w = f2bf(tmp[i].w);
        *(ushort4*)(xs + row * XST + kq * 4) = u;
    }
    __syncthreads();

    // ---- MFMA: each wave computes one 16x16 tile (rowtile rt, coltile ct) ----
    const int wave = tid >> 6, lane = tid & 63;
    const int rt = wave & 1, ct = wave >> 1;
    const int m = lane & 15, quad = lane >> 4;

    const unsigned short* arow = xs + (rt * 16 + m) * XST + quad * 8;
    const unsigned short* brow = PTbf + (size_t)(ct * 16 + m) * 512 + quad * 8;

    f32x4 acc = {0.f, 0.f, 0.f, 0.f};
    #pragma unroll
    for (int ks = 0; ks < 16; ++ks) {
        s16x8 a = *(const s16x8*)(arow + ks * 32);
        s16x8 b = *(const s16x8*)(brow + ks * 32);
        acc = __builtin_amdgcn_mfma_f32_16x16x32_bf16(a, b, acc, 0, 0, 0);
    }
    __syncthreads();                          // all A-frag LDS reads done before overlay

    // ---- epilogue: sigmoid(mask * score / sqrt(32)) -> w0 overlay ----
    // C/D layout: col = lane&15, row = quad*4 + reg
    #pragma unroll
    for (int r = 0; r < 4; ++r) {
        int rowL = rt * 16 + quad * 4 + r;
        float mr = (mask[rowBase + rowL] != 0) ? 1.0f : 0.0f;
        w0f[rowL * 33 + ct * 16 + m] = sigmoidf_(mr * acc[r] * INV_SCALE);
    }
    __syncthreads();

    // ---- hidden layer: w1[row][k] = sigmoid(sum_j w0[row][j]*hd[j][k] / scale) ----
    {
        const int k = tid & 31, slot = tid >> 5;  // 8 slots x 4 rows
        #pragma unroll
        for (int t = 0; t < 4; ++t) {
            int row = slot + 8 * t;
            float s = 0.f;
            #pragma unroll
            for (int j = 0; j < 32; ++j)
                s = fmaf(w0f[row * 33 + j], hd[j * 32 + k], s);
            w1f[row * 33 + k] = sigmoidf_(s * INV_SCALE);
        }
    }
    __syncthreads();

    // ---- evaluator + sign-tag mask into v ----
    if (tid < 32) {
        float s = 0.f;
        #pragma unroll
        for (int k = 0; k < 32; ++k)
            s = fmaf(w1f[tid * 33 + k], ev[k], s);
        float val = sigmoidf_(s * INV_SCALE);       // in (0,1), never 0
        v[rowBase + tid] = (mask[rowBase + tid] != 0) ? val : -val;
    }
}

// ---- per-b stats + in-place coefficient write; mask is v's sign bit ----
__global__ __launch_bounds__(256) void kCoeff(float* __restrict__ v) {
    const int b = blockIdx.x, tid = threadIdx.x;
    __shared__ float sr[8];

    float ee[8], mm[8];
    float z = 0.f, dm = 0.f;
    #pragma unroll
    for (int i = 0; i < 8; ++i) {
        int idx = b * S_ + i * 256 + tid;
        float raw = v[idx];
        mm[i] = (raw > 0.f) ? 1.0f : 0.0f;
        ee[i] = __expf(fabsf(raw));          // no max-sub needed: |v| in (0,1)
        z += ee[i];
        dm = fmaf(mm[i], ee[i], dm);
    }
    #pragma unroll
    for (int o = 32; o > 0; o >>= 1) {
        z  += __shfl_down(z, o);
        dm += __shfl_down(dm, o);
    }
    if ((tid & 63) == 0) { sr[tid >> 6] = z; sr[4 + (tid >> 6)] = dm; }
    __syncthreads();
    float Z  = (sr[0] + sr[1]) + (sr[2] + sr[3]);
    float DM = (sr[4] + sr[5]) + (sr[6] + sr[7]);
    float invDen = 1.0f / (DM + 1e-12f * Z);
    #pragma unroll
    for (int i = 0; i < 8; ++i) {
        int idx = b * S_ + i * 256 + tid;
        v[idx] = mm[i] * ee[i] * invDen;
    }
}

// ---- weighted sum, direct to out: block = (b, 64-float d-chunk), 1024 thr ----
__global__ __launch_bounds__(1024) void kOut(
        const float* __restrict__ inp, const float* __restrict__ coeff,
        float* __restrict__ out) {
    const int b = blockIdx.x >> 3, dc = blockIdx.x & 7;
    const int tid = threadIdx.x;
    const int sg = tid >> 4, dl = tid & 15;   // 64 s-groups x 16 float4-lanes
    __shared__ float  cw[S_];
    __shared__ float4 red[1024];

    cw[tid]        = coeff[b * S_ + tid];
    cw[tid + 1024] = coeff[b * S_ + tid + 1024];
    __syncthreads();

    const float4* xp = (const float4*)inp + (size_t)b * S_ * 128 + dc * 16 + dl;
    float4 a0 = make_float4(0,0,0,0), a1 = a0, a2 = a0, a3 = a0;
    #pragma unroll 2
    for (int i = 0; i < 32; i += 4) {
        int s0 = sg + 64 * i;
        float4 x0 = xp[(size_t)(s0      ) * 128];
        float4 x1 = xp[(size_t)(s0 +  64) * 128];
        float4 x2 = xp[(size_t)(s0 + 128) * 128];
        float4 x3 = xp[(size_t)(s0 + 192) * 128];
        float c0 = cw[s0], c1 = cw[s0 + 64], c2 = cw[s0 + 128], c3 = cw[s0 + 192];
        a0.x = fmaf(c0, x0.x, a0.x); a0.y = fmaf(c0, x0.y, a0.y);
        a0.z = fmaf(c0, x0.z, a0.z); a0.w = fmaf(c0, x0.w, a0.w);
        a1.x = fmaf(c1, x1.x, a1.x); a1.y = fmaf(c1, x1.y, a1.y);
        a1.z = fmaf(c1, x1.z, a1.z); a1.w = fmaf(c1, x1.w, a1.w);
        a2.x = fmaf(c2, x2.x, a2.x); a2.y = fmaf(c2, x2.y, a2.y);
        a2.z = fmaf(c2, x2.z, a2.z); a2.w = fmaf(c2, x2.w, a2.w);
        a3.x = fmaf(c3, x3.x, a3.x); a3.y = fmaf(c3, x3.y, a3.y);
        a3.z = fmaf(c3, x3.z, a3.z); a3.w = fmaf(c3, x3.w, a3.w);
    }
    float4 a;
    a.x = (a0.x + a1.x) + (a2.x + a3.x);
    a.y = (a0.y + a1.y) + (a2.y + a3.y);
    a.z = (a0.z + a1.z) + (a2.z + a3.z);
    a.w = (a0.w + a1.w) + (a2.w + a3.w);
    red[tid] = a;
    __syncthreads();

    #pragma unroll
    for (int h = 32; h >= 1; h >>= 1) {
        if (sg < h) {
            float4 p = red[(sg + h) * 16 + dl];
            float4 q = red[tid];
            q.x += p.x; q.y += p.y; q.z += p.z; q.w += p.w;
            red[tid] = q;
        }
        __syncthreads();
    }
    if (tid < 16)
        ((float4*)out)[b * 128 + dc * 16 + tid] = red[tid];
}

extern "C" void kernel_launch(void* const* d_in, const int* in_sizes, int n_in,
                              void* d_out, int out_size, void* d_ws, size_t ws_size,
                              hipStream_t stream) {
    const float* inp  = (const float*)d_in[0];
    const int*   mask = (const int*)d_in[1];
    const float* proj = (const float*)d_in[2];
    const float* hid  = (const float*)d_in[3];   // [1][32][32]
    const float* ev   = (const float*)d_in[4];   // [32]
    float* out = (float*)d_out;

    unsigned short* PTbf = (unsigned short*)d_ws;
    float* v = (float*)d_ws + 8192;              // after 32 KB of PTbf

    kTransposeBf<<<64, 256, 0, stream>>>(proj, PTbf);
    kScores     <<<BS_ / 32, 256, 0, stream>>>(inp, mask, PTbf, hid, ev, v);
    kCoeff      <<<B_, 256, 0, stream>>>(v);
    kOut        <<<B_ * 8, 1024, 0, stream>>>(inp, v, out);
}

// Round 5
// 221.581 us; speedup vs baseline: 2.5310x; 1.0730x over previous
//
#include <hip/hip_runtime.h>

#define B_   32
#define S_   2048
#define D_   512
#define H_   32
#define BS_  (B_*S_)
#define INV_SCALE 0.17677669529663689f   // 1/sqrt(32)

// workspace layout (bytes):
// [0, 32768):            PTbf    ushort[32][512]   bf16 transposed projector
// [32768, 49152):        zdm     float2[2048]      per-block (Z, DM) partials
// [49152, 4243456):      partial float[2048][512]  per-block numerator partials

typedef short  s16x8 __attribute__((ext_vector_type(8)));
typedef float  f32x4 __attribute__((ext_vector_type(4)));

__device__ __forceinline__ float sigmoidf_(float x) {
    return 1.0f / (1.0f + __expf(-x));
}

__device__ __forceinline__ unsigned short f2bf(float f) {
    unsigned u = __float_as_uint(f);
    u += 0x7fffu + ((u >> 16) & 1u);     // round-to-nearest-even
    return (unsigned short)(u >> 16);
}

// ---------------- transpose projector to bf16: PTbf[j][d] = bf16(P[d][j]) ----
__global__ void kTransposeBf(const float* __restrict__ P, unsigned short* __restrict__ PTbf) {
    int o = blockIdx.x * 256 + threadIdx.x;      // 16384 total
    int j = o >> 9, d = o & 511;
    PTbf[o] = f2bf(P[d * H_ + j]);
}

// ---- fused scores + unnormalized weighted partial sum: 32 rows/block ----
#define XST 520                               // bf16 row stride in LDS (512 + 8 pad)

__global__ __launch_bounds__(256) void kFused(
        const float* __restrict__ inp, const int* __restrict__ mask,
        const unsigned short* __restrict__ PTbf, const float* __restrict__ hd,
        const float* __restrict__ ev,
        float* __restrict__ partial, float2* __restrict__ zdm) {
    __shared__ unsigned short xs[32 * XST];   // 33280 B, stays live to the end
    __shared__ float w0f[32 * 33];            // 4224 B
    __shared__ float w1f[32 * 33];            // 4224 B
    __shared__ float cs[32];                  // unnormalized coefficients

    const int tid = threadIdx.x;
    const int blk = blockIdx.x;
    const int rowBase = blk * 32;

    // ---- stage x tile (32 rows x 512 fp32 = 64 KB) -> LDS bf16, coalesced ----
    const float4* g = (const float4*)inp + (size_t)rowBase * 128;
    float4 tmp[16];
    #pragma unroll
    for (int i = 0; i < 16; ++i)
        tmp[i] = g[i * 256 + tid];            // flat index == row*128 + kq
    #pragma unroll
    for (int i = 0; i < 16; ++i) {
        int fi = i * 256 + tid;
        int row = fi >> 7, kq = fi & 127;
        ushort4 u;
        u.x = f2bf(tmp[i].x); u.y = f2bf(tmp[i].y);
        u.z = f2bf(tmp[i].z); u.w = f2bf(tmp[i].w);
        *(ushort4*)(xs + row * XST + kq * 4) = u;
    }
    __syncthreads();

    // ---- MFMA: each wave one 16x16 tile (rowtile rt, coltile ct) ----
    const int wave = tid >> 6, lane = tid & 63;
    const int rt = wave & 1, ct = wave >> 1;
    const int m = lane & 15, quad = lane >> 4;

    const unsigned short* arow = xs + (rt * 16 + m) * XST + quad * 8;
    const unsigned short* brow = PTbf + (size_t)(ct * 16 + m) * 512 + quad * 8;

    f32x4 acc = {0.f, 0.f, 0.f, 0.f};
    #pragma unroll
    for (int ks = 0; ks < 16; ++ks) {
        s16x8 a = *(const s16x8*)(arow + ks * 32);
        s16x8 b = *(const s16x8*)(brow + ks * 32);
        acc = __builtin_amdgcn_mfma_f32_16x16x32_bf16(a, b, acc, 0, 0, 0);
    }

    // ---- epilogue: sigmoid(mask * score / sqrt(32)) -> w0f (disjoint from xs) ----
    // C/D layout: col = lane&15, row = quad*4 + reg
    #pragma unroll
    for (int r = 0; r < 4; ++r) {
        int rowL = rt * 16 + quad * 4 + r;
        float mr = (mask[rowBase + rowL] != 0) ? 1.0f : 0.0f;
        w0f[rowL * 33 + ct * 16 + m] = sigmoidf_(mr * acc[r] * INV_SCALE);
    }
    __syncthreads();

    // ---- hidden layer: w1[row][k] = sigmoid(sum_j w0[row][j]*hd[j][k] / scale) ----
    {
        const int k = tid & 31, slot = tid >> 5;  // 8 slots x 4 rows
        #pragma unroll
        for (int t = 0; t < 4; ++t) {
            int row = slot + 8 * t;
            float s = 0.f;
            #pragma unroll
            for (int j = 0; j < 32; ++j)
                s = fmaf(w0f[row * 33 + j], hd[j * 32 + k], s);
            w1f[row * 33 + k] = sigmoidf_(s * INV_SCALE);
        }
    }
    __syncthreads();

    // ---- evaluator -> c_s = m*exp(v_s); block partial (Z, DM) via wave 0 ----
    if (tid < 64) {
        float e = 0.f, mm = 0.f;
        if (tid < 32) {
            float s = 0.f;
            #pragma unroll
            for (int k = 0; k < 32; ++k)
                s = fmaf(w1f[tid * 33 + k], ev[k], s);
            float val = sigmoidf_(s * INV_SCALE);    // in (0,1): exp safe, no max-sub
            e  = __expf(val);
            mm = (mask[rowBase + tid] != 0) ? 1.0f : 0.0f;
            cs[tid] = mm * e;
        }
        float z = e, dm = mm * e;
        #pragma unroll
        for (int o = 32; o > 0; o >>= 1) {
            z  += __shfl_down(z, o);
            dm += __shfl_down(dm, o);
        }
        if (tid == 0) zdm[blk] = make_float2(z, dm);
    }
    __syncthreads();

    // ---- numerator partial: thread owns d = {2*tid, 2*tid+1} ----
    float a0 = 0.f, a1 = 0.f;
    #pragma unroll 8
    for (int row = 0; row < 32; ++row) {
        unsigned u = *(const unsigned*)(xs + row * XST + 2 * tid); // conflict-free
        float x0 = __uint_as_float(u << 16);           // element 2*tid
        float x1 = __uint_as_float(u & 0xffff0000u);   // element 2*tid+1
        float c = cs[row];                              // broadcast
        a0 = fmaf(c, x0, a0);
        a1 = fmaf(c, x1, a1);
    }
    ((float2*)(partial + (size_t)blk * 512))[tid] = make_float2(a0, a1);
}

// ---- reduce 64 partials per b, normalize, write out ----
__global__ __launch_bounds__(256) void kReduce(
        const float* __restrict__ partial, const float2* __restrict__ zdm,
        float* __restrict__ out) {
    const int b = blockIdx.x, tid = threadIdx.x;
    __shared__ float sInv;

    if (tid < 64) {
        float2 p = zdm[b * 64 + tid];
        float z = p.x, dm = p.y;
        #pragma unroll
        for (int o = 32; o > 0; o >>= 1) {
            z  += __shfl_down(z, o);
            dm += __shfl_down(dm, o);
        }
        if (tid == 0) sInv = 1.0f / (dm + 1e-12f * z);
    }
    __syncthreads();

    const float2* pp = (const float2*)partial + (size_t)b * 64 * 256 + tid;
    float a0 = 0.f, b0 = 0.f, a1 = 0.f, b1 = 0.f;
    float a2 = 0.f, b2 = 0.f, a3 = 0.f, b3 = 0.f;
    #pragma unroll
    for (int i = 0; i < 64; i += 4) {          // 4 loads in flight
        float2 p0 = pp[(size_t)(i + 0) * 256];
        float2 p1 = pp[(size_t)(i + 1) * 256];
        float2 p2 = pp[(size_t)(i + 2) * 256];
        float2 p3 = pp[(size_t)(i + 3) * 256];
        a0 += p0.x; b0 += p0.y; a1 += p1.x; b1 += p1.y;
        a2 += p2.x; b2 += p2.y; a3 += p3.x; b3 += p3.y;
    }
    const float inv = sInv;
    float2 r;
    r.x = ((a0 + a1) + (a2 + a3)) * inv;
    r.y = ((b0 + b1) + (b2 + b3)) * inv;
    ((float2*)out)[b * 256 + tid] = r;
}

extern "C" void kernel_launch(void* const* d_in, const int* in_sizes, int n_in,
                              void* d_out, int out_size, void* d_ws, size_t ws_size,
                              hipStream_t stream) {
    const float* inp  = (const float*)d_in[0];
    const int*   mask = (const int*)d_in[1];
    const float* proj = (const float*)d_in[2];
    const float* hid  = (const float*)d_in[3];   // [1][32][32]
    const float* ev   = (const float*)d_in[4];   // [32]
    float* out = (float*)d_out;

    unsigned short* PTbf = (unsigned short*)d_ws;
    float2* zdm     = (float2*)((char*)d_ws + 32768);
    float*  partial = (float*)((char*)d_ws + 49152);

    kTransposeBf<<<64, 256, 0, stream>>>(proj, PTbf);
    kFused      <<<BS_ / 32, 256, 0, stream>>>(inp, mask, PTbf, hid, ev, partial, zdm);
    kReduce     <<<B_, 256, 0, stream>>>(partial, zdm, out);
}